// Round 1
// baseline (201.749 us; speedup 1.0000x reference)
//
#include <hip/hip_runtime.h>
#include <math.h>

// Problem constants
#define D 64
#define K 512
#define NROWS 65536
#define DECAY 0.99f
#define ONE_MINUS_DECAY (1.0f - 0.99f)
#define COMMIT 0.25f

// ws layout (float offsets)
#define WS_DWT    0              // [K][D] = 32768  dw accumulator (transposed)
#define WS_COUNTS 32768          // [K]   = 512
#define WS_LPART  33280          // [32]  loss partial sums
#define WS_ZERO4  8336           // float4 count zeroed by prep (33344 floats)
#define WS_ESQ    33344          // [K]   ||e_k||^2
#define WS_ET     33856          // [K][D] fp32 embeddings transposed (gather)
#define WS_EF     66624          // f16 MFMA B-fragments [16 tiles][4 kstep][2 half][64 lanes] x 16B = 32768 floats
#define WS_STABLE 99392          // [K]
#define WS_DEBIAS 99904          // [1]

// out layout (float offsets) — unchanged
#define OUT_Q     0
#define OUT_LOSS  4194304
#define OUT_PERP  4194305
#define OUT_IDX   4194306
#define OUT_NEMB  4259842
#define OUT_HCS   4292610
#define OUT_HDW   4293122

typedef _Float16 f16x8 __attribute__((ext_vector_type(8)));
typedef float    f32x16 __attribute__((ext_vector_type(16)));

// ---------------- prep: zero accum + e_t + ||e||^2 + f16 hi/lo B-fragments ---
// B-fragment layout for v_mfma_f32_32x32x16_f16:
//   lane l supplies col = tile*32 + (l&31), k = (l>>5)*8 + j (j=0..7 contiguous)
// fragment block index i = ((t*4 + s)*2 + h)*64 + l  (s=kstep, h=0 hi / 1 lo)
__global__ void vq_prep(const float* __restrict__ emb,  // [D][K]
                        float* __restrict__ ws)
{
    int i = blockIdx.x * 256 + threadIdx.x;   // 0..32767 (128 blocks)
    if (i < WS_ZERO4) {                       // zero dw_t + counts + loss parts
        ((float4*)ws)[i] = make_float4(0.f, 0.f, 0.f, 0.f);
    }
    if (i < K * D) {                          // e_t[k][d] = emb[d][k]
        int k = i >> 6, d = i & 63;
        ws[WS_ET + i] = emb[d * K + k];
    }
    if (i < K) {                              // ||e_k||^2
        float s = 0.f;
        for (int d = 0; d < D; ++d) { float v = emb[d * K + i]; s += v * v; }
        ws[WS_ESQ + i] = s;
    }
    if (i < 8192) {                           // f16 hi/lo fragment buffer
        int l = i & 63, h = (i >> 6) & 1, s = (i >> 7) & 3, t = i >> 9;
        int col = t * 32 + (l & 31);
        int d0  = s * 16 + ((l >> 5) << 3);
        f16x8 frag;
#pragma unroll
        for (int j = 0; j < 8; ++j) {
            float v = emb[(d0 + j) * K + col];
            _Float16 hv = (_Float16)v;
            frag[j] = h ? (_Float16)(v - (float)hv) : hv;
        }
        ((f16x8*)(ws + WS_EF))[i] = frag;
    }
}

// ---------------- main: MFMA distances + argmin + gather + scatter -----------
// Per block: 256 threads = 4 waves; each wave owns 32 rows (one 32x32 MFMA
// row-tile) and is fully independent: no __syncthreads anywhere.
// Distance dot-products via 3-term f16 split (xh*eh + xh*el + xl*eh),
// fp32-equivalent ordering.  C/D layout (guide-verified): col = lane&31,
// row = (reg&3) + 8*(reg>>2) + 4*(lane>>5).
__global__ __launch_bounds__(256, 2)
void vq_main(const float* __restrict__ x,     // [N][D]
             const float* __restrict__ e_sq,  // [K]
             const float* __restrict__ e_t,   // [K][D] fp32
             const float* __restrict__ ef,    // f16 fragment buffer
             float* __restrict__ out_q,       // [N][D]
             float* __restrict__ out_idx,     // [N] (float)
             float* __restrict__ dw_t,        // [K][D] atomic accum
             float* __restrict__ counts,      // [K]
             float* __restrict__ loss_parts)  // [32]
{
    __shared__ int idx_s[4][32];

    const int tid  = threadIdx.x;
    const int w    = tid >> 6;
    const int l    = tid & 63;
    const int lr   = l & 31;       // A-row / B-col / C-col within tile
    const int hb   = l >> 5;       // k-group select
    const int row0 = blockIdx.x * 128 + w * 32;

    // ---- A fragments: this lane supplies row (row0+lr), k = s*16 + hb*8 + j
    f16x8 ah[4], al[4];
    {
        const float* xr = x + (size_t)(row0 + lr) * D + hb * 8;
#pragma unroll
        for (int s = 0; s < 4; ++s) {
            float4 f0 = *(const float4*)(xr + s * 16);
            float4 f1 = *(const float4*)(xr + s * 16 + 4);
            float f[8] = {f0.x, f0.y, f0.z, f0.w, f1.x, f1.y, f1.z, f1.w};
#pragma unroll
            for (int j = 0; j < 8; ++j) {
                _Float16 hv = (_Float16)f[j];
                ah[s][j] = hv;
                al[s][j] = (_Float16)(f[j] - (float)hv);
            }
        }
    }

    float best[16];
    int   bestk[16];
#pragma unroll
    for (int r = 0; r < 16; ++r) { best[r] = 3.0e38f; bestk[r] = 0; }

    const f16x8* __restrict__ efv = (const f16x8*)ef;

#pragma unroll 2
    for (int t = 0; t < 16; ++t) {
        f16x8 bh[4], bl[4];
#pragma unroll
        for (int s = 0; s < 4; ++s) {
            bh[s] = efv[(t * 8 + s * 2 + 0) * 64 + l];
            bl[s] = efv[(t * 8 + s * 2 + 1) * 64 + l];
        }
        // two independent accumulation chains (ksteps 0-1 and 2-3)
        f32x16 a0 = {}, a1 = {};
#pragma unroll
        for (int s = 0; s < 2; ++s) {
            a0 = __builtin_amdgcn_mfma_f32_32x32x16_f16(al[s], bh[s], a0, 0, 0, 0);
            a0 = __builtin_amdgcn_mfma_f32_32x32x16_f16(ah[s], bl[s], a0, 0, 0, 0);
            a0 = __builtin_amdgcn_mfma_f32_32x32x16_f16(ah[s], bh[s], a0, 0, 0, 0);
        }
#pragma unroll
        for (int s = 2; s < 4; ++s) {
            a1 = __builtin_amdgcn_mfma_f32_32x32x16_f16(al[s], bh[s], a1, 0, 0, 0);
            a1 = __builtin_amdgcn_mfma_f32_32x32x16_f16(ah[s], bl[s], a1, 0, 0, 0);
            a1 = __builtin_amdgcn_mfma_f32_32x32x16_f16(ah[s], bh[s], a1, 0, 0, 0);
        }
        f32x16 acc = a0 + a1;

        // fold: score = ||e||^2 - 2 x.e ; candidate col is fixed per lane
        float eq = e_sq[t * 32 + lr];
        int   kc = t * 32 + lr;
#pragma unroll
        for (int r = 0; r < 16; ++r) {
            float sc = fmaf(-2.0f, acc[r], eq);
            if (sc < best[r]) { best[r] = sc; bestk[r] = kc; }  // k ascends with t
        }
    }

    // ---- argmin reduce across the 32 lanes sharing each row set -------------
#pragma unroll
    for (int r = 0; r < 16; ++r) {
        float b = best[r]; int bk = bestk[r];
#pragma unroll
        for (int m = 16; m >= 1; m >>= 1) {
            float ob  = __shfl_xor(b, m, 64);
            int   obk = __shfl_xor(bk, m, 64);
            if (ob < b || (ob == b && obk < bk)) { b = ob; bk = obk; }
        }
        if (lr == 0) idx_s[w][(r & 3) + 8 * (r >> 2) + 4 * hb] = bk;
    }
    // same-wave LDS write->read: compiler inserts lgkmcnt wait, no barrier.

    // ---- gather + loss + out_q + dw scatter (one pass, per-wave) -----------
    float lsum = 0.f;
#pragma unroll
    for (int it = 0; it < 8; ++it) {
        int i = it * 256 + l * 4;
        int r = i >> 6, d = i & 63;
        int kk = idx_s[w][r];
        float4 q  = *(const float4*)&e_t[kk * D + d];
        float4 xv = *(const float4*)&x[(size_t)(row0 + r) * D + d];
        float dx = q.x - xv.x, dy = q.y - xv.y, dz = q.z - xv.z, dwv = q.w - xv.w;
        lsum += dx * dx + dy * dy + dz * dz + dwv * dwv;
        *(float4*)&out_q[(size_t)(row0 + r) * D + d] = q;
        atomicAdd(&dw_t[kk * D + d + 0], xv.x);
        atomicAdd(&dw_t[kk * D + d + 1], xv.y);
        atomicAdd(&dw_t[kk * D + d + 2], xv.z);
        atomicAdd(&dw_t[kk * D + d + 3], xv.w);
    }
#pragma unroll
    for (int m = 32; m >= 1; m >>= 1) lsum += __shfl_xor(lsum, m, 64);
    if (l == 0) atomicAdd(&loss_parts[blockIdx.x & 31], lsum);

    if (l < 32) {
        int kk = idx_s[w][l];
        out_idx[row0 + l] = (float)kk;
        atomicAdd(&counts[kk], 1.0f);
    }
}

// ---------------- finalize A: scalars (1 block, shuffle reductions) ----------
__global__ void vq_final_a(const float* __restrict__ counts,
                           const float* __restrict__ loss_parts,
                           const float* __restrict__ ema_csh,  // [K]
                           const int*   __restrict__ counter,
                           float* __restrict__ out_loss,
                           float* __restrict__ out_perp,
                           float* __restrict__ out_hcs,        // [K]
                           float* __restrict__ ws_stable,      // [K]
                           float* __restrict__ ws_debias)      // [1]
{
    __shared__ float s_upd[8], s_ent[8], s_n, s_e;

    const int k = threadIdx.x;  // 512 threads
    const float c = counts[k];
    const float hid = ema_csh[k] * DECAY + c * ONE_MINUS_DECAY;
    out_hcs[k] = hid;

    const int   cnt    = counter[0] + 1;
    const float debias = 1.0f - powf(DECAY, (float)cnt);
    const float upd    = hid / debias;

    const float p   = c * (1.0f / (float)NROWS);
    const float ent = p * logf(p + 1e-10f);

    float vu = upd, ve = ent;
#pragma unroll
    for (int m = 32; m >= 1; m >>= 1) {
        vu += __shfl_xor(vu, m, 64);
        ve += __shfl_xor(ve, m, 64);
    }
    if ((k & 63) == 0) { s_upd[k >> 6] = vu; s_ent[k >> 6] = ve; }
    __syncthreads();
    if (k == 0) {
        float n = 0.f, e = 0.f;
        for (int i = 0; i < 8; ++i) { n += s_upd[i]; e += s_ent[i]; }
        s_n = n; s_e = e;
    }
    __syncthreads();

    const float n = s_n;
    ws_stable[k] = (upd + 1e-5f) / (n + (float)K * 1e-5f) * n;

    if (k < 32) {
        float lp = loss_parts[k];
#pragma unroll
        for (int m = 16; m >= 1; m >>= 1) lp += __shfl_xor(lp, m, 64);
        if (k == 0) {
            ws_debias[0] = debias;
            out_loss[0]  = COMMIT * lp / (float)((size_t)NROWS * D);
            out_perp[0]  = expf(-s_e);
        }
    }
}

// ---------------- finalize B: hdw + new embeddings ---------------------------
__global__ void vq_final_b(const float* __restrict__ dw_t,      // [K][D]
                           const float* __restrict__ ema_dwh,   // [D][K]
                           const float* __restrict__ ws_stable, // [K]
                           const float* __restrict__ ws_debias,
                           float* __restrict__ out_nemb,        // [D][K]
                           float* __restrict__ out_hdw)         // [D][K]
{
    int i = blockIdx.x * 256 + threadIdx.x;  // 0..32767 (128 blocks)
    int d = i >> 9, kk = i & (K - 1);
    float hdw = ema_dwh[i] * DECAY + dw_t[kk * D + d] * ONE_MINUS_DECAY;
    out_hdw[i]  = hdw;
    out_nemb[i] = (hdw / ws_debias[0]) / ws_stable[kk];
}

// ---------------- launch ------------------------------------------------------
extern "C" void kernel_launch(void* const* d_in, const int* in_sizes, int n_in,
                              void* d_out, int out_size, void* d_ws, size_t ws_size,
                              hipStream_t stream)
{
    const float* x_in    = (const float*)d_in[0];   // [64,32,32,64]
    const float* emb     = (const float*)d_in[1];   // [64,512]
    const float* ema_csh = (const float*)d_in[2];   // [512]
    const float* ema_dwh = (const float*)d_in[3];   // [64,512]
    const int*   counter = (const int*)d_in[4];     // [1]

    float* ws  = (float*)d_ws;
    float* out = (float*)d_out;

    vq_prep<<<128, 256, 0, stream>>>(emb, ws);

    vq_main<<<NROWS / 128, 256, 0, stream>>>(
        x_in, ws + WS_ESQ, ws + WS_ET, ws + WS_EF,
        out + OUT_Q, out + OUT_IDX,
        ws + WS_DWT, ws + WS_COUNTS, ws + WS_LPART);

    vq_final_a<<<1, K, 0, stream>>>(
        ws + WS_COUNTS, ws + WS_LPART, ema_csh, counter,
        out + OUT_LOSS, out + OUT_PERP, out + OUT_HCS,
        ws + WS_STABLE, ws + WS_DEBIAS);

    vq_final_b<<<128, 256, 0, stream>>>(
        ws + WS_DWT, ema_dwh, ws + WS_STABLE, ws + WS_DEBIAS,
        out + OUT_NEMB, out + OUT_HDW);
}

// Round 2
// 155.662 us; speedup vs baseline: 1.2961x; 1.2961x over previous
//
#include <hip/hip_runtime.h>
#include <math.h>

// Problem constants
#define D 64
#define K 512
#define NROWS 65536
#define DECAY 0.99f
#define ONE_MINUS_DECAY (1.0f - 0.99f)
#define COMMIT 0.25f

// ws layout (float offsets)
#define WS_DWT    0              // [K][D] = 32768  dw accumulator (transposed)
#define WS_COUNTS 32768          // [K]   = 512
#define WS_LPART  33280          // [32]  loss partial sums
#define WS_ZERO4  8336           // float4 count zeroed by prep (33344 floats)
#define WS_ESQ    33344          // [K]   ||e_k||^2
#define WS_ET     33856          // [K][D] fp32 embeddings transposed (gather)
#define WS_EF     66624          // f16 MFMA B-fragments: 8192 x 16B = 32768 floats

// out layout (float offsets) — unchanged
#define OUT_Q     0
#define OUT_LOSS  4194304
#define OUT_PERP  4194305
#define OUT_IDX   4194306
#define OUT_NEMB  4259842
#define OUT_HCS   4292610
#define OUT_HDW   4293122

typedef _Float16 f16x8 __attribute__((ext_vector_type(8)));
typedef float    f32x16 __attribute__((ext_vector_type(16)));

// ---------------- prep: zero accum + e_t + ||e||^2 + f16 hi/lo B-fragments ---
// B-fragment layout for v_mfma_f32_32x32x16_f16:
//   lane l supplies col = tile*32 + (l&31), k = (l>>5)*8 + j (j=0..7)
// fragment block index i = ((t*4 + s)*2 + h)*64 + l  (s=kstep, h=0 hi / 1 lo)
__global__ void vq_prep(const float* __restrict__ emb,  // [D][K]
                        float* __restrict__ ws)
{
    int i = blockIdx.x * 256 + threadIdx.x;   // 0..32767 (128 blocks)
    if (i < WS_ZERO4) {                       // zero dw_t + counts + loss parts
        ((float4*)ws)[i] = make_float4(0.f, 0.f, 0.f, 0.f);
    }
    if (i < K * D) {                          // e_t[k][d] = emb[d][k]
        int k = i >> 6, d = i & 63;
        ws[WS_ET + i] = emb[d * K + k];
    }
    if (i < K) {                              // ||e_k||^2
        float s = 0.f;
        for (int d = 0; d < D; ++d) { float v = emb[d * K + i]; s += v * v; }
        ws[WS_ESQ + i] = s;
    }
    if (i < 8192) {                           // f16 hi/lo fragment buffer
        int l = i & 63, h = (i >> 6) & 1, s = (i >> 7) & 3, t = i >> 9;
        int col = t * 32 + (l & 31);
        int d0  = s * 16 + ((l >> 5) << 3);
        f16x8 frag;
#pragma unroll
        for (int j = 0; j < 8; ++j) {
            float v = emb[(d0 + j) * K + col];
            _Float16 hv = (_Float16)v;
            frag[j] = h ? (_Float16)(v - (float)hv) : hv;
        }
        ((f16x8*)(ws + WS_EF))[i] = frag;
    }
}

// ---------------- main: MFMA distances + argmin + gather + scatter -----------
// 4 waves/block; each wave owns 32 rows (one 32x32 MFMA row-tile), fully
// independent — no __syncthreads.  Distances via 3-term f16 split.
// C/D layout: col = lane&31, row = (reg&3) + 8*(reg>>2) + 4*(lane>>5).
__global__ __launch_bounds__(256, 2)
void vq_main(const float* __restrict__ x,     // [N][D]
             const float* __restrict__ e_sq,  // [K]
             const float* __restrict__ e_t,   // [K][D] fp32
             const float* __restrict__ ef,    // f16 fragment buffer
             float* __restrict__ out_q,       // [N][D]
             float* __restrict__ out_idx,     // [N] (float)
             float* __restrict__ dw_t,        // [K][D] atomic accum
             float* __restrict__ counts,      // [K]
             float* __restrict__ loss_parts)  // [32]
{
    __shared__ int idx_s[4][32];

    const int tid  = threadIdx.x;
    const int w    = tid >> 6;
    const int l    = tid & 63;
    const int lr   = l & 31;       // A-row / B-col / C-col within tile
    const int hb   = l >> 5;       // k-group select
    const int row0 = blockIdx.x * 128 + w * 32;

    // ---- A fragments: this lane supplies row (row0+lr), k = s*16 + hb*8 + j
    f16x8 ah[4], al[4];
    {
        const float* xr = x + (size_t)(row0 + lr) * D + hb * 8;
#pragma unroll
        for (int s = 0; s < 4; ++s) {
            float4 f0 = *(const float4*)(xr + s * 16);
            float4 f1 = *(const float4*)(xr + s * 16 + 4);
            float f[8] = {f0.x, f0.y, f0.z, f0.w, f1.x, f1.y, f1.z, f1.w};
#pragma unroll
            for (int j = 0; j < 8; ++j) {
                _Float16 hv = (_Float16)f[j];
                ah[s][j] = hv;
                al[s][j] = (_Float16)(f[j] - (float)hv);
            }
        }
    }

    float best[16];
    int   bestk[16];
#pragma unroll
    for (int r = 0; r < 16; ++r) { best[r] = 3.0e38f; bestk[r] = 0; }

    const f16x8* __restrict__ efv = (const f16x8*)ef;

#pragma unroll 2
    for (int t = 0; t < 16; ++t) {
        f16x8 bh[4], bl[4];
#pragma unroll
        for (int s = 0; s < 4; ++s) {
            bh[s] = efv[(t * 8 + s * 2 + 0) * 64 + l];
            bl[s] = efv[(t * 8 + s * 2 + 1) * 64 + l];
        }
        f32x16 a0 = {}, a1 = {};
#pragma unroll
        for (int s = 0; s < 2; ++s) {
            a0 = __builtin_amdgcn_mfma_f32_32x32x16_f16(al[s], bh[s], a0, 0, 0, 0);
            a0 = __builtin_amdgcn_mfma_f32_32x32x16_f16(ah[s], bl[s], a0, 0, 0, 0);
            a0 = __builtin_amdgcn_mfma_f32_32x32x16_f16(ah[s], bh[s], a0, 0, 0, 0);
        }
#pragma unroll
        for (int s = 2; s < 4; ++s) {
            a1 = __builtin_amdgcn_mfma_f32_32x32x16_f16(al[s], bh[s], a1, 0, 0, 0);
            a1 = __builtin_amdgcn_mfma_f32_32x32x16_f16(ah[s], bl[s], a1, 0, 0, 0);
            a1 = __builtin_amdgcn_mfma_f32_32x32x16_f16(ah[s], bh[s], a1, 0, 0, 0);
        }
        f32x16 acc = a0 + a1;

        float eq = e_sq[t * 32 + lr];
        int   kc = t * 32 + lr;
#pragma unroll
        for (int r = 0; r < 16; ++r) {
            float sc = fmaf(-2.0f, acc[r], eq);
            if (sc < best[r]) { best[r] = sc; bestk[r] = kc; }  // k ascends with t
        }
    }

    // ---- argmin reduce across the 32 lanes sharing each row set -------------
#pragma unroll
    for (int r = 0; r < 16; ++r) {
        float b = best[r]; int bk = bestk[r];
#pragma unroll
        for (int m = 16; m >= 1; m >>= 1) {
            float ob  = __shfl_xor(b, m, 64);
            int   obk = __shfl_xor(bk, m, 64);
            if (ob < b || (ob == b && obk < bk)) { b = ob; bk = obk; }
        }
        if (lr == 0) idx_s[w][(r & 3) + 8 * (r >> 2) + 4 * hb] = bk;
    }
    // same-wave LDS write->read: compiler inserts lgkmcnt wait, no barrier.

    // ---- unified gather + loss + out_q + dw scatter, ROW-CONTIGUOUS --------
    // Per iteration every instruction has 64 consecutive lanes on ONE row
    // (uniform kk, d = lane): maximal line-merging for loads, stores and
    // atomics (4B/atomic of write traffic, not 16B).
    float lsum = 0.f;
#pragma unroll
    for (int r = 0; r < 32; ++r) {
        const int kk = idx_s[w][r];
        const float q  = e_t[kk * D + l];
        const float xv = x[(size_t)(row0 + r) * D + l];
        const float df = q - xv;
        lsum += df * df;
        out_q[(size_t)(row0 + r) * D + l] = q;
        atomicAdd(&dw_t[kk * D + l], xv);
    }
#pragma unroll
    for (int m = 32; m >= 1; m >>= 1) lsum += __shfl_xor(lsum, m, 64);
    if (l == 0) atomicAdd(&loss_parts[blockIdx.x & 31], lsum);

    if (l < 32) {
        int kk = idx_s[w][l];
        out_idx[row0 + l] = (float)kk;
        atomicAdd(&counts[kk], 1.0f);
    }
}

// ---------------- finalize (merged): scalars + hdw + new embeddings ----------
// 128 blocks x 256.  Every block redundantly recomputes debias and the
// n-reduction from counts (2KB, L2-resident) — removes the 1-block
// dependency dispatch entirely.
__global__ __launch_bounds__(256)
void vq_final(const float* __restrict__ counts,      // [K]
              const float* __restrict__ loss_parts,  // [32]
              const float* __restrict__ ema_csh,     // [K]
              const int*   __restrict__ counter,
              const float* __restrict__ ema_dwh,     // [D][K]
              const float* __restrict__ dw_t,        // [K][D]
              float* __restrict__ out_loss,
              float* __restrict__ out_perp,
              float* __restrict__ out_hcs,           // [K]
              float* __restrict__ out_nemb,          // [D][K]
              float* __restrict__ out_hdw)           // [D][K]
{
    __shared__ float s_red[4];
    __shared__ float s_n;

    const int tid = threadIdx.x;
    const int b   = blockIdx.x;

    const int   cnt    = counter[0] + 1;
    const float debias = 1.0f - powf(DECAY, (float)cnt);

    const float c0 = counts[tid];
    const float c1 = counts[tid + 256];
    const float hid0 = ema_csh[tid] * DECAY + c0 * ONE_MINUS_DECAY;
    const float hid1 = ema_csh[tid + 256] * DECAY + c1 * ONE_MINUS_DECAY;
    const float upd0 = hid0 / debias;
    const float upd1 = hid1 / debias;

    // n = sum over all 512 updated cluster sizes (block-wide reduce)
    float v = upd0 + upd1;
#pragma unroll
    for (int m = 32; m >= 1; m >>= 1) v += __shfl_xor(v, m, 64);
    if ((tid & 63) == 0) s_red[tid >> 6] = v;
    __syncthreads();
    if (tid == 0) s_n = s_red[0] + s_red[1] + s_red[2] + s_red[3];
    __syncthreads();
    const float n = s_n;

    // this block's 256-element slice of [D][K]
    const int i  = b * 256 + tid;          // 0..32767
    const int kk = i & (K - 1);            // = tid + 256*(b&1)
    const int d  = i >> 9;
    const float updk   = (b & 1) ? upd1 : upd0;
    const float stable = (updk + 1e-5f) / (n + (float)K * 1e-5f) * n;
    const float hdw = ema_dwh[i] * DECAY + dw_t[kk * D + d] * ONE_MINUS_DECAY;
    out_hdw[i]  = hdw;
    out_nemb[i] = (hdw / debias) / stable;

    if (b == 0) {
        out_hcs[tid]       = hid0;
        out_hcs[tid + 256] = hid1;

        const float inv = 1.0f / (float)NROWS;
        float p0 = c0 * inv, p1 = c1 * inv;
        float ve = p0 * logf(p0 + 1e-10f) + p1 * logf(p1 + 1e-10f);
#pragma unroll
        for (int m = 32; m >= 1; m >>= 1) ve += __shfl_xor(ve, m, 64);
        __syncthreads();                    // safe re-use of s_red
        if ((tid & 63) == 0) s_red[tid >> 6] = ve;
        __syncthreads();
        if (tid < 32) {
            float lp = loss_parts[tid];
#pragma unroll
            for (int m = 16; m >= 1; m >>= 1) lp += __shfl_xor(lp, m, 64);
            if (tid == 0) {
                out_loss[0] = COMMIT * lp / (float)((size_t)NROWS * D);
                out_perp[0] = expf(-(s_red[0] + s_red[1] + s_red[2] + s_red[3]));
            }
        }
    }
}

// ---------------- launch ------------------------------------------------------
extern "C" void kernel_launch(void* const* d_in, const int* in_sizes, int n_in,
                              void* d_out, int out_size, void* d_ws, size_t ws_size,
                              hipStream_t stream)
{
    const float* x_in    = (const float*)d_in[0];   // [64,32,32,64]
    const float* emb     = (const float*)d_in[1];   // [64,512]
    const float* ema_csh = (const float*)d_in[2];   // [512]
    const float* ema_dwh = (const float*)d_in[3];   // [64,512]
    const int*   counter = (const int*)d_in[4];     // [1]

    float* ws  = (float*)d_ws;
    float* out = (float*)d_out;

    vq_prep<<<128, 256, 0, stream>>>(emb, ws);

    vq_main<<<NROWS / 128, 256, 0, stream>>>(
        x_in, ws + WS_ESQ, ws + WS_ET, ws + WS_EF,
        out + OUT_Q, out + OUT_IDX,
        ws + WS_DWT, ws + WS_COUNTS, ws + WS_LPART);

    vq_final<<<128, 256, 0, stream>>>(
        ws + WS_COUNTS, ws + WS_LPART, ema_csh, counter, ema_dwh, ws + WS_DWT,
        out + OUT_LOSS, out + OUT_PERP, out + OUT_HCS,
        out + OUT_NEMB, out + OUT_HDW);
}

// Round 3
// 147.176 us; speedup vs baseline: 1.3708x; 1.0577x over previous
//
#include <hip/hip_runtime.h>
#include <math.h>

// Problem constants
#define D 64
#define K 512
#define NROWS 65536
#define DECAY 0.99f
#define ONE_MINUS_DECAY (1.0f - 0.99f)
#define COMMIT 0.25f

// ws layout (float offsets)
#define WS_DWT    0              // [K][D] = 32768 floats, dw accumulator (zeroed)
#define WS_CNT    32768          // [K] int histogram / rank counters (zeroed)
#define WS_LPART  33280          // [32] loss partial sums (zeroed)
#define WS_ZERO4  8336           // float4 count zeroed by prep (33344 floats)
#define WS_ESQ    33344          // [K]   ||e_k||^2
#define WS_ET     33856          // [K][D] fp32 embeddings transposed (gather)
#define WS_EF     66624          // f16 MFMA B-fragments: 8192 x 16B = 32768 floats
#define WS_PK     99392          // [N] int packed (rank<<9 | k)
#define WS_PERM   164928         // [N] int packed (row<<9 | k)
// total ws requirement: (164928 + 65536) * 4 = 921,856 bytes

// out layout (float offsets) — unchanged
#define OUT_Q     0
#define OUT_LOSS  4194304
#define OUT_PERP  4194305
#define OUT_IDX   4194306
#define OUT_NEMB  4259842
#define OUT_HCS   4292610
#define OUT_HDW   4293122

typedef _Float16 f16x8 __attribute__((ext_vector_type(8)));
typedef float    f32x16 __attribute__((ext_vector_type(16)));

// ---------------- prep: zero accum + e_t + ||e||^2 + f16 hi/lo B-fragments ---
// B-fragment layout for v_mfma_f32_32x32x16_f16:
//   lane l supplies col = tile*32 + (l&31), k = (l>>5)*8 + j (j=0..7)
// fragment block index i = ((t*4 + s)*2 + h)*64 + l  (s=kstep, h=0 hi / 1 lo)
__global__ void vq_prep(const float* __restrict__ emb,  // [D][K]
                        float* __restrict__ ws)
{
    int i = blockIdx.x * 256 + threadIdx.x;   // 0..32767 (128 blocks)
    if (i < WS_ZERO4) {                       // zero dw_t + cnt + loss parts
        ((float4*)ws)[i] = make_float4(0.f, 0.f, 0.f, 0.f);
    }
    if (i < K * D) {                          // e_t[k][d] = emb[d][k]
        int k = i >> 6, d = i & 63;
        ws[WS_ET + i] = emb[d * K + k];
    }
    if (i < K) {                              // ||e_k||^2
        float s = 0.f;
        for (int d = 0; d < D; ++d) { float v = emb[d * K + i]; s += v * v; }
        ws[WS_ESQ + i] = s;
    }
    if (i < 8192) {                           // f16 hi/lo fragment buffer
        int l = i & 63, h = (i >> 6) & 1, s = (i >> 7) & 3, t = i >> 9;
        int col = t * 32 + (l & 31);
        int d0  = s * 16 + ((l >> 5) << 3);
        f16x8 frag;
#pragma unroll
        for (int j = 0; j < 8; ++j) {
            float v = emb[(d0 + j) * K + col];
            _Float16 hv = (_Float16)v;
            frag[j] = h ? (_Float16)(v - (float)hv) : hv;
        }
        ((f16x8*)(ws + WS_EF))[i] = frag;
    }
}

// ---------------- main: MFMA distances + argmin + gather (NO dw atomics) -----
// 4 waves/block; each wave owns 32 rows (one 32x32 MFMA row-tile), fully
// independent — no __syncthreads.  Distances via 3-term f16 split.
// C/D layout: col = lane&31, row = (reg&3) + 8*(reg>>2) + 4*(lane>>5).
__global__ __launch_bounds__(256, 2)
void vq_main(const float* __restrict__ x,     // [N][D]
             const float* __restrict__ e_sq,  // [K]
             const float* __restrict__ e_t,   // [K][D] fp32
             const float* __restrict__ ef,    // f16 fragment buffer
             float* __restrict__ out_q,       // [N][D]
             float* __restrict__ out_idx,     // [N] (float)
             int*   __restrict__ cnt,         // [K] int histogram (rank source)
             int*   __restrict__ pk,          // [N] packed (rank<<9 | k)
             float* __restrict__ loss_parts)  // [32]
{
    __shared__ int idx_s[4][32];

    const int tid  = threadIdx.x;
    const int w    = tid >> 6;
    const int l    = tid & 63;
    const int lr   = l & 31;       // A-row / B-col / C-col within tile
    const int hb   = l >> 5;       // k-group select
    const int row0 = blockIdx.x * 128 + w * 32;

    // ---- A fragments: this lane supplies row (row0+lr), k = s*16 + hb*8 + j
    f16x8 ah[4], al[4];
    {
        const float* xr = x + (size_t)(row0 + lr) * D + hb * 8;
#pragma unroll
        for (int s = 0; s < 4; ++s) {
            float4 f0 = *(const float4*)(xr + s * 16);
            float4 f1 = *(const float4*)(xr + s * 16 + 4);
            float f[8] = {f0.x, f0.y, f0.z, f0.w, f1.x, f1.y, f1.z, f1.w};
#pragma unroll
            for (int j = 0; j < 8; ++j) {
                _Float16 hv = (_Float16)f[j];
                ah[s][j] = hv;
                al[s][j] = (_Float16)(f[j] - (float)hv);
            }
        }
    }

    float best[16];
    int   bestk[16];
#pragma unroll
    for (int r = 0; r < 16; ++r) { best[r] = 3.0e38f; bestk[r] = 0; }

    const f16x8* __restrict__ efv = (const f16x8*)ef;

#pragma unroll 2
    for (int t = 0; t < 16; ++t) {
        f16x8 bh[4], bl[4];
#pragma unroll
        for (int s = 0; s < 4; ++s) {
            bh[s] = efv[(t * 8 + s * 2 + 0) * 64 + l];
            bl[s] = efv[(t * 8 + s * 2 + 1) * 64 + l];
        }
        f32x16 a0 = {}, a1 = {};
#pragma unroll
        for (int s = 0; s < 2; ++s) {
            a0 = __builtin_amdgcn_mfma_f32_32x32x16_f16(al[s], bh[s], a0, 0, 0, 0);
            a0 = __builtin_amdgcn_mfma_f32_32x32x16_f16(ah[s], bl[s], a0, 0, 0, 0);
            a0 = __builtin_amdgcn_mfma_f32_32x32x16_f16(ah[s], bh[s], a0, 0, 0, 0);
        }
#pragma unroll
        for (int s = 2; s < 4; ++s) {
            a1 = __builtin_amdgcn_mfma_f32_32x32x16_f16(al[s], bh[s], a1, 0, 0, 0);
            a1 = __builtin_amdgcn_mfma_f32_32x32x16_f16(ah[s], bl[s], a1, 0, 0, 0);
            a1 = __builtin_amdgcn_mfma_f32_32x32x16_f16(ah[s], bh[s], a1, 0, 0, 0);
        }
        f32x16 acc = a0 + a1;

        float eq = e_sq[t * 32 + lr];
        int   kc = t * 32 + lr;
#pragma unroll
        for (int r = 0; r < 16; ++r) {
            float sc = fmaf(-2.0f, acc[r], eq);
            if (sc < best[r]) { best[r] = sc; bestk[r] = kc; }  // k ascends with t
        }
    }

    // ---- argmin reduce across the 32 lanes sharing each row set -------------
#pragma unroll
    for (int r = 0; r < 16; ++r) {
        float b = best[r]; int bk = bestk[r];
#pragma unroll
        for (int m = 16; m >= 1; m >>= 1) {
            float ob  = __shfl_xor(b, m, 64);
            int   obk = __shfl_xor(bk, m, 64);
            if (ob < b || (ob == b && obk < bk)) { b = ob; bk = obk; }
        }
        if (lr == 0) idx_s[w][(r & 3) + 8 * (r >> 2) + 4 * hb] = bk;
    }
    // same-wave LDS write->read: compiler inserts lgkmcnt wait, no barrier.

    // ---- gather + loss + out_q, ROW-CONTIGUOUS (no dw scatter here) --------
    float lsum = 0.f;
#pragma unroll
    for (int r = 0; r < 32; ++r) {
        const int kk = idx_s[w][r];
        const float q  = e_t[kk * D + l];
        const float xv = x[(size_t)(row0 + r) * D + l];
        const float df = q - xv;
        lsum += df * df;
        out_q[(size_t)(row0 + r) * D + l] = q;
    }
#pragma unroll
    for (int m = 32; m >= 1; m >>= 1) lsum += __shfl_xor(lsum, m, 64);
    if (l == 0) atomicAdd(&loss_parts[blockIdx.x & 31], lsum);

    // indices + rank-in-bucket (int atomic returns old = rank)
    if (l < 32) {
        int kk = idx_s[w][l];
        out_idx[row0 + l] = (float)kk;
        int rank = atomicAdd(&cnt[kk], 1);
        pk[row0 + l] = (rank << 9) | kk;
    }
}

// ---------------- perm build: per-block redundant scan + scatter -------------
// 64 blocks x 512.  Each block scans the 512-entry histogram in LDS
// (Hillis-Steele), then scatters its 1024 rows: perm[offs[k]+rank] = row|k.
__global__ __launch_bounds__(512)
void vq_perm(const int* __restrict__ cnt,   // [K]
             const int* __restrict__ pk,    // [N] (rank<<9 | k)
             int* __restrict__ perm)        // [N] (row<<9 | k), k-sorted
{
    __shared__ int s[K];

    const int t = threadIdx.x;            // 0..511
    const int c0 = cnt[t];
    s[t] = c0;
    __syncthreads();
#pragma unroll
    for (int off = 1; off < K; off <<= 1) {
        int v = (t >= off) ? s[t - off] : 0;
        __syncthreads();
        s[t] += v;
        __syncthreads();
    }
    const int offs = s[t] - c0;           // exclusive prefix
    __syncthreads();
    s[t] = offs;
    __syncthreads();

#pragma unroll
    for (int it = 0; it < 2; ++it) {
        int row = blockIdx.x * 1024 + it * 512 + t;
        int v   = pk[row];
        int kk  = v & (K - 1);
        int rk  = v >> 9;
        perm[s[kk] + rk] = (row << 9) | kk;
    }
}

// ---------------- dw segmented reduce over k-sorted perm ---------------------
// 512 blocks x 256 = 2048 waves; wave w owns perm chunk [32w, 32w+32).
// lane = d.  k is wave-uniform per entry -> flush only at run boundaries
// (~2 atomic instrs per wave instead of 32).
__global__ __launch_bounds__(256, 2)
void vq_dwsum(const int* __restrict__ perm,  // [N] (row<<9 | k)
              const float* __restrict__ x,   // [N][D]
              float* __restrict__ dw_t)      // [K][D] accumulate
{
    const int w = (blockIdx.x * 256 + threadIdx.x) >> 6;  // 0..2047
    const int l = threadIdx.x & 63;

    int pv = 0;
    if (l < 32) pv = perm[w * 32 + l];

    float sum = 0.f;
    int kcur = -1;
#pragma unroll
    for (int e = 0; e < 32; ++e) {
        int pe  = __shfl(pv, e, 64);
        int kk  = pe & (K - 1);
        int row = pe >> 9;
        float xv = x[(size_t)row * D + l];
        if (kk != kcur) {                       // wave-uniform branch
            if (kcur >= 0) atomicAdd(&dw_t[kcur * D + l], sum);
            kcur = kk; sum = xv;
        } else {
            sum += xv;
        }
    }
    atomicAdd(&dw_t[kcur * D + l], sum);
}

// ---------------- finalize: scalars + hdw + new embeddings -------------------
// 128 blocks x 256.  Every block redundantly recomputes debias and the
// n-reduction from the histogram (2KB, L2-resident).
__global__ __launch_bounds__(256)
void vq_final(const int*   __restrict__ cnt,         // [K]
              const float* __restrict__ loss_parts,  // [32]
              const float* __restrict__ ema_csh,     // [K]
              const int*   __restrict__ counter,
              const float* __restrict__ ema_dwh,     // [D][K]
              const float* __restrict__ dw_t,        // [K][D]
              float* __restrict__ out_loss,
              float* __restrict__ out_perp,
              float* __restrict__ out_hcs,           // [K]
              float* __restrict__ out_nemb,          // [D][K]
              float* __restrict__ out_hdw)           // [D][K]
{
    __shared__ float s_red[4];
    __shared__ float s_n;

    const int tid = threadIdx.x;
    const int b   = blockIdx.x;

    const int   cntr   = counter[0] + 1;
    const float debias = 1.0f - powf(DECAY, (float)cntr);

    const float c0 = (float)cnt[tid];
    const float c1 = (float)cnt[tid + 256];
    const float hid0 = ema_csh[tid] * DECAY + c0 * ONE_MINUS_DECAY;
    const float hid1 = ema_csh[tid + 256] * DECAY + c1 * ONE_MINUS_DECAY;
    const float upd0 = hid0 / debias;
    const float upd1 = hid1 / debias;

    float v = upd0 + upd1;
#pragma unroll
    for (int m = 32; m >= 1; m >>= 1) v += __shfl_xor(v, m, 64);
    if ((tid & 63) == 0) s_red[tid >> 6] = v;
    __syncthreads();
    if (tid == 0) s_n = s_red[0] + s_red[1] + s_red[2] + s_red[3];
    __syncthreads();
    const float n = s_n;

    const int i  = b * 256 + tid;          // 0..32767
    const int kk = i & (K - 1);
    const int d  = i >> 9;
    const float updk   = (b & 1) ? upd1 : upd0;
    const float stable = (updk + 1e-5f) / (n + (float)K * 1e-5f) * n;
    const float hdw = ema_dwh[i] * DECAY + dw_t[kk * D + d] * ONE_MINUS_DECAY;
    out_hdw[i]  = hdw;
    out_nemb[i] = (hdw / debias) / stable;

    if (b == 0) {
        out_hcs[tid]       = hid0;
        out_hcs[tid + 256] = hid1;

        const float inv = 1.0f / (float)NROWS;
        float p0 = c0 * inv, p1 = c1 * inv;
        float ve = p0 * logf(p0 + 1e-10f) + p1 * logf(p1 + 1e-10f);
#pragma unroll
        for (int m = 32; m >= 1; m >>= 1) ve += __shfl_xor(ve, m, 64);
        __syncthreads();
        if ((tid & 63) == 0) s_red[tid >> 6] = ve;
        __syncthreads();
        if (tid < 32) {
            float lp = loss_parts[tid];
#pragma unroll
            for (int m = 16; m >= 1; m >>= 1) lp += __shfl_xor(lp, m, 64);
            if (tid == 0) {
                out_loss[0] = COMMIT * lp / (float)((size_t)NROWS * D);
                out_perp[0] = expf(-(s_red[0] + s_red[1] + s_red[2] + s_red[3]));
            }
        }
    }
}

// ---------------- launch ------------------------------------------------------
extern "C" void kernel_launch(void* const* d_in, const int* in_sizes, int n_in,
                              void* d_out, int out_size, void* d_ws, size_t ws_size,
                              hipStream_t stream)
{
    const float* x_in    = (const float*)d_in[0];   // [64,32,32,64]
    const float* emb     = (const float*)d_in[1];   // [64,512]
    const float* ema_csh = (const float*)d_in[2];   // [512]
    const float* ema_dwh = (const float*)d_in[3];   // [64,512]
    const int*   counter = (const int*)d_in[4];     // [1]

    float* ws  = (float*)d_ws;
    float* out = (float*)d_out;

    vq_prep<<<128, 256, 0, stream>>>(emb, ws);

    vq_main<<<NROWS / 128, 256, 0, stream>>>(
        x_in, ws + WS_ESQ, ws + WS_ET, ws + WS_EF,
        out + OUT_Q, out + OUT_IDX,
        (int*)(ws + WS_CNT), (int*)(ws + WS_PK), ws + WS_LPART);

    vq_perm<<<64, 512, 0, stream>>>(
        (const int*)(ws + WS_CNT), (const int*)(ws + WS_PK),
        (int*)(ws + WS_PERM));

    vq_dwsum<<<512, 256, 0, stream>>>(
        (const int*)(ws + WS_PERM), x_in, ws + WS_DWT);

    vq_final<<<128, 256, 0, stream>>>(
        (const int*)(ws + WS_CNT), ws + WS_LPART, ema_csh, counter,
        ema_dwh, ws + WS_DWT,
        out + OUT_LOSS, out + OUT_PERP, out + OUT_HCS,
        out + OUT_NEMB, out + OUT_HDW);
}